// Round 3
// baseline (516.165 us; speedup 1.0000x reference)
//
#include <hip/hip_runtime.h>

#define DIM 4096
#define TOTAL 16384
#define STATE_LEN 3
#define BATCH 8
#define NSLOTS 256
#define TVEC (TOTAL / 4)                   // 4096 float4 per x row
#define NCONV4 (DIM * TVEC)                // 16777216 float4 of conv output
#define SROW (DIM * STATE_LEN)             // 12288 floats per slot
#define S4_PER_SLOT (SROW / 4)             // 3072 float4 per slot
#define NSTATE4 (NSLOTS * S4_PER_SLOT)     // 786432 float4 of states
#define NBLK 2048
#define NTHREADS (NBLK * 256)              // 524288 threads; NCONV4/NTHREADS = 32 exactly

typedef float floatx4 __attribute__((ext_vector_type(4)));

// Grid-stride persistent kernel, no LDS, no barriers.
// Loop 1 (short): full out_states write (copy untouched slots, recompute touched).
// Loop 2 (32 iters): conv output, one float4 per iteration.
__global__ __launch_bounds__(256) void fused_kernel(
    const float* __restrict__ x, const float* __restrict__ weight,
    const float* __restrict__ cs, const int* __restrict__ qsl,
    const int* __restrict__ cache_indices, const int* __restrict__ init_mode,
    const int* __restrict__ pad_p, const int* __restrict__ res_p,
    float* __restrict__ out, float* __restrict__ out_states)
{
    // Uniform params: constant-index loads -> SGPRs (s_load), no LDS, no barrier.
    int q[BATCH + 1];
    #pragma unroll
    for (int k = 0; k <= BATCH; k++) q[k] = qsl[k];
    int ci_[BATCH], im_[BATCH];
    #pragma unroll
    for (int k = 0; k < BATCH; k++) { ci_[k] = cache_indices[k]; im_[k] = init_mode[k]; }
    const int pad = pad_p[0];
    const float wres = res_p[0] ? 1.0f : 0.0f;

    const int tid = blockIdx.x * 256 + threadIdx.x;
    const floatx4* __restrict__ x4 = (const floatx4*)x;
    const floatx4* __restrict__ cs4 = (const floatx4*)cs;

    // ---------------- states loop (786432 float4, 1-2 iters for low tids) ----------------
    for (int f = tid; f < NSTATE4; f += NTHREADS) {
        int slot = f / S4_PER_SLOT;
        floatx4 cv = cs4[f];                       // coalesced; common case is plain copy
        // slot -> batch lookup via select chain (constant indices only)
        bool found = false; int start = 0, end = 0, imv = 0;
        #pragma unroll
        for (int k = 0; k < BATCH; k++) {
            bool m = (ci_[k] == slot) && (ci_[k] != pad);
            start = m ? q[k] : start;
            end   = m ? q[k + 1] : end;
            imv   = m ? im_[k] : imv;
            found = found || m;
        }
        if (!found) {
            __builtin_nontemporal_store(cv, (floatx4*)out_states + f);
        } else {
            int L = end - start;
            bool init = (imv != 0);
            int base = (f - slot * S4_PER_SLOT) * 4;   // float index within slot (= d*3 + j)
            float r[4];
            #pragma unroll
            for (int e = 0; e < 4; e++) {
                int idx = base + e;
                int d = idx / 3;
                int j = idx - d * 3;
                int gx = end + j - STATE_LEN;
                float val;
                if (gx >= start) {
                    val = x[(size_t)d * TOTAL + gx];
                } else if (init) {
                    int sidx = L + j;                  // gx<start => L+j<3
                    if (sidx > STATE_LEN - 1) sidx = STATE_LEN - 1;
                    val = cs[(size_t)slot * SROW + d * STATE_LEN + sidx];
                } else {
                    val = 0.f;
                }
                r[e] = val;
            }
            floatx4 rv = (floatx4){r[0], r[1], r[2], r[3]};
            __builtin_nontemporal_store(rv, (floatx4*)out_states + f);
        }
    }

    // ---------------- conv loop (exactly 32 iterations per thread) ----------------
    #pragma unroll 2
    for (int v = tid; v < NCONV4; v += NTHREADS) {
        int d  = v >> 12;                // v / TVEC
        int tv = v & (TVEC - 1);
        int t0 = tv << 2;

        floatx4 cur = x4[v];
        int pv = (tv > 0) ? (v - 1) : v;           // unconditional, in-bounds load
        floatx4 prev = x4[pv];
        if (tv == 0) prev = (floatx4){0.f, 0.f, 0.f, 0.f};

        floatx4 w = ((const floatx4*)weight)[d];
        w.w += wres;                               // fold residual into the x[t] tap

        // win[3+i] = x[t0+i]; x[t-dd] = win[3+i-dd]
        float win[7] = {prev.y, prev.z, prev.w, cur.x, cur.y, cur.z, cur.w};

        // qs = qsl[seg(t)] via select chain (q sorted ascending; rightmost match wins)
        int qs_lo = 0, qs_hi = 0;
        #pragma unroll
        for (int k = 1; k < BATCH; k++) {
            qs_lo = (t0     >= q[k]) ? q[k] : qs_lo;
            qs_hi = (t0 + 3 >= q[k]) ? q[k] : qs_hi;
        }

        floatx4 o;
        if ((qs_lo == qs_hi) && (t0 - qs_lo >= 3)) {
            // fast path: whole tile from x (t0>=3 => tv>=1 => prev valid)
            o.x = w.x * win[0] + w.y * win[1] + w.z * win[2] + w.w * win[3];
            o.y = w.x * win[1] + w.y * win[2] + w.z * win[3] + w.w * win[4];
            o.z = w.x * win[2] + w.y * win[3] + w.z * win[4] + w.w * win[5];
            o.w = w.x * win[3] + w.y * win[4] + w.z * win[5] + w.w * win[6];
        } else {
            float res4[4];
            #pragma unroll
            for (int ii = 0; ii < 4; ii++) {
                int t = t0 + ii;
                int qs = 0, civ = ci_[0], imv = im_[0];
                #pragma unroll
                for (int k = 1; k < BATCH; k++) {
                    bool m = (t >= q[k]);
                    qs  = m ? q[k]   : qs;
                    civ = m ? ci_[k] : civ;
                    imv = m ? im_[k] : imv;
                }
                int p = t - qs;
                float xt = win[3 + ii];
                float acc;
                if (p >= 3) {
                    acc = w.x * win[ii] + w.y * win[ii + 1] + w.z * win[ii + 2] + w.w * xt;
                } else {
                    bool valid = (civ != pad);
                    int slot = valid ? civ : 0;
                    bool use_init = valid && (imv != 0);
                    const float* csrow = cs + ((size_t)slot * DIM + d) * STATE_LEN;
                    float xm1 = (p >= 1) ? win[ii + 2] : (use_init ? csrow[2 + p] : 0.f);
                    float xm2 = (p >= 2) ? win[ii + 1] : (use_init ? csrow[1 + p] : 0.f);
                    float xm3 =                          (use_init ? csrow[0 + p] : 0.f);
                    acc = w.x * xm3 + w.y * xm2 + w.z * xm1 + w.w * xt;
                }
                res4[ii] = acc;
            }
            o = (floatx4){res4[0], res4[1], res4[2], res4[3]};
        }
        __builtin_nontemporal_store(o, (floatx4*)out + v);
    }
}

extern "C" void kernel_launch(void* const* d_in, const int* in_sizes, int n_in,
                              void* d_out, int out_size, void* d_ws, size_t ws_size,
                              hipStream_t stream) {
    const float* x      = (const float*)d_in[0];
    const float* weight = (const float*)d_in[1];
    const float* cs     = (const float*)d_in[2];
    const int*   qsl    = (const int*)d_in[3];
    const int*   ci     = (const int*)d_in[4];
    const int*   im     = (const int*)d_in[5];
    const int*   pad    = (const int*)d_in[6];
    const int*   res    = (const int*)d_in[7];

    float* out        = (float*)d_out;
    float* out_states = out + (size_t)DIM * TOTAL;

    fused_kernel<<<NBLK, 256, 0, stream>>>(
        x, weight, cs, qsl, ci, im, pad, res, out, out_states);
}